// Round 12
// baseline (126.951 us; speedup 1.0000x reference)
//
#include <hip/hip_runtime.h>

// GraphUnpoolingMesh, output layout (flat f32):
//   [ new_x : (N+E)*F | ei_row0 : M | ei_row1 : M ],  M = 3E + 3T
//
// Ladder: 153 -> 146 -> 136 (R8 XCD-affine src buckets) -> 133.7 (R10 slim)
// -> 126.5 (R11 copy+edge folds). R11 analysis: fabric-bound floor ~110 us
// (721 MB L2-miss traffic @ 7.2 TB/s + scatter/launch). The ~16 us gap is
// latency slack: only 2 row-loads per group in flight. R12: 4 slots per
// 32-lane group (8 row-loads in flight), 4 copy-rows per group.

#define F 128
#define F4 32                    // float4 per row
#define BSHIFT 10                // 1024 nodes / bucket = 0.5 MB of x
#define SLOTS 8192               // slots per bucket (mean fill 6122, 26 sigma)
#define SPB 256                  // slot-chunks per bucket (32 slots/block)
#define CPB 32                   // copy-chunks per bucket (32 rows/block)
#define BPB (SPB + CPB)          // blocks per bucket = 288
#define CHUNK 2048               // edges per scatter block

typedef float f32x4 __attribute__((ext_vector_type(4)));
typedef unsigned long long u64;

__device__ __forceinline__ void nt_store4(f32x4 v, f32x4* p) {
    asm volatile("global_store_dwordx4 %0, %1, off sc0 sc1 nt"
                 :: "v"(p), "v"(v) : "memory");
}
__device__ __forceinline__ void nt_store1(float v, float* p) {
    asm volatile("global_store_dword %0, %1, off sc0 sc1 nt"
                 :: "v"(p), "v"(v) : "memory");
}

// K1: init per-bucket cursors only (98 ints).
__global__ void init_kernel(int* __restrict__ cursor, int NB) {
    const int t = threadIdx.x;
    if (t < NB) cursor[t] = t * SLOTS;
}

// K2: scatter edges into bucket slot regions + emit ALL edge-index rows.
// Tuple = (pk<<32)|dst with pk = e | (src&1023)<<20  (src = bucket<<10 | low).
__global__ __launch_bounds__(256) void scatter_kernel(
        const int* __restrict__ ei0, const int* __restrict__ ei1,
        int* __restrict__ cursor, u64* __restrict__ tup,
        float* __restrict__ r0, float* __restrict__ r1,
        int N, int E, int TT3, int NB) {
    __shared__ int lh[128];
    __shared__ int lbase[128];
    const int t = threadIdx.x;
    if (t < 128) lh[t] = 0;
    __syncthreads();
    const int base = blockIdx.x * CHUNK;
    int s[8], d[8], bk[8], rk[8];
#pragma unroll
    for (int i = 0; i < 8; ++i) {
        const int e = base + i * 256 + t;
        if (e < E) {
            s[i] = ei0[e];
            d[i] = ei1[e];
            bk[i] = s[i] >> BSHIFT;
            rk[i] = atomicAdd(&lh[bk[i]], 1);
            const float fs = (float)s[i], fd = (float)d[i], fm = (float)(N + e);
            nt_store1(fs, &r0[e]);
            nt_store1(fd, &r1[e]);
            nt_store1(fs, &r0[E + e]);
            nt_store1(fm, &r1[E + e]);
            nt_store1(fm, &r0[2 * E + e]);
            nt_store1(fd, &r1[2 * E + e]);
        } else {
            bk[i] = -1;
        }
        if (e < TT3) {
            const int tt = e / 3;
            const int k = e - 3 * tt;
            const int ii = N + 3 * tt;
            nt_store1((float)(ii + k), &r0[3 * E + e]);
            nt_store1((float)((k < 2) ? (ii + k + 1) : ii), &r1[3 * E + e]);
        }
    }
    __syncthreads();
    if (t < NB) {
        const int c = lh[t];
        lbase[t] = c ? atomicAdd(&cursor[t], c) : 0;
    }
    __syncthreads();
#pragma unroll
    for (int i = 0; i < 8; ++i) {
        if (bk[i] >= 0) {
            const int e = base + i * 256 + t;
            const int pos = lbase[bk[i]] + rk[i];
            if (pos < (bk[i] + 1) * SLOTS) {      // overflow guard (26-sigma)
                const u64 pk = (u64)(e | ((s[i] & 1023) << 20));
                tup[pos] = (pk << 32) | (unsigned)d[i];
            }
        }
    }
}

// K3: XCD-affine bucket sweep. Per bucket: 256 slot-chunks (32 midpoint
// slots each, 4 per group -> 8 row-loads in flight) + 32 copy-chunks.
__global__ __launch_bounds__(256) void main_kernel(
        const f32x4* __restrict__ x4,
        const u64* __restrict__ tup, const int* __restrict__ cursor,
        f32x4* __restrict__ out4,
        int N, int NB, int MBlk) {
    const unsigned b = blockIdx.x;
    if (b >= (unsigned)MBlk) return;
    const int xcd = b & 7;
    const int seq = b >> 3;
    const int bucket = xcd + 8 * (seq / BPB);
    if (bucket >= NB) return;
    const int r = seq % BPB;
    const int lane = threadIdx.x & 31;
    const int g = threadIdx.x >> 5;

    if (r < SPB) {
        // ---- midpoint slot-chunk: 4 slots per group ----
        const int cnt = cursor[bucket] - bucket * SLOTS;  // fill count
        const int si0 = r * 32 + g * 4;
        if (si0 >= cnt) return;
        const int p0 = bucket * SLOTS + si0;
        const int nbase = bucket << BSHIFT;
        const int nv = min(4, cnt - si0);

        // Phase 1: issue all loads (tuples broadcast, then 2*nv row loads).
        u64 tv[4];
        f32x4 av[4], bv[4];
        int ev[4];
#pragma unroll
        for (int j = 0; j < 4; ++j)
            tv[j] = (j < nv) ? tup[p0 + j] : 0;
#pragma unroll
        for (int j = 0; j < 4; ++j) {
            const int dj = (int)(tv[j] & 0xffffffffu);
            const int pkj = (int)(tv[j] >> 32);
            const int sj = nbase | (pkj >> 20);
            ev[j] = pkj & 0xFFFFF;
            if (j < nv) {
                av[j] = x4[(size_t)sj * F4 + lane];   // src: L2-resident
                bv[j] = x4[(size_t)dj * F4 + lane];   // dst: random (L3)
            }
        }
        // Phase 2: compute + store.
#pragma unroll
        for (int j = 0; j < 4; ++j) {
            if (j < nv)
                nt_store4(0.5f * (av[j] + bv[j]),
                          &out4[(size_t)(N + ev[j]) * F4 + lane]);
        }
    } else {
        // ---- copy-chunk: 4 of this bucket's own node rows per group ----
        const int cr = r - SPB;                   // 0..31
        const long long row0 = ((long long)bucket << BSHIFT) + cr * 32 + g * 4;
        f32x4 v[4];
        const int nv = (int)min((long long)4, (long long)N - row0);
#pragma unroll
        for (int j = 0; j < 4; ++j)
            if (j < nv) v[j] = x4[(row0 + j) * F4 + lane];
#pragma unroll
        for (int j = 0; j < 4; ++j)
            if (j < nv) nt_store4(v[j], &out4[(row0 + j) * F4 + lane]);
    }
}

extern "C" void kernel_launch(void* const* d_in, const int* in_sizes, int n_in,
                              void* d_out, int out_size, void* d_ws, size_t ws_size,
                              hipStream_t stream) {
    const float* x = (const float*)d_in[0];
    const int* ei = (const int*)d_in[1];

    const int N = in_sizes[0] / F;                 // 100000
    const int E = in_sizes[1] / 2;                 // 600000
    const int T = (E > 2) ? (E - 2 + 2) / 3 : 0;   // ceil((E-2)/3)
    const int M = 3 * E + 3 * T;

    const int* ei0 = ei;
    const int* ei1 = ei + E;

    float* out = (float*)d_out;
    float* r0 = out + (size_t)(N + E) * F;
    float* r1 = r0 + M;

    // ws layout: [0..4095] cursors | [4096..] u64 slot array
    int* cursor = (int*)d_ws;
    u64* tup = (u64*)((char*)d_ws + 4096);

    const int NB = (N + (1 << BSHIFT) - 1) >> BSHIFT;   // 98
    const int NBpad = (NB + 7) & ~7;                    // 104
    const int MBlk = NBpad * BPB;                       // 29952 blocks

    init_kernel<<<1, 128, 0, stream>>>(cursor, NB);
    scatter_kernel<<<(E + CHUNK - 1) / CHUNK, 256, 0, stream>>>(
        ei0, ei1, cursor, tup, r0, r1, N, E, 3 * T, NB);
    main_kernel<<<MBlk, 256, 0, stream>>>(
        (const f32x4*)x, tup, cursor, (f32x4*)out, N, NB, MBlk);
}